// Round 1
// baseline (274.244 us; speedup 1.0000x reference)
//
#include <hip/hip_runtime.h>
#include <hip/hip_bf16.h>

using bf16 = __hip_bfloat16;
typedef __attribute__((ext_vector_type(8))) short short8;   // 8 bf16 = 4 VGPRs (MFMA a/b frag)
typedef __attribute__((ext_vector_type(4))) float floatx4;  // MFMA c/d frag

#define NEG_INF (-__builtin_huge_valf())

// async global->LDS, 16B per lane. LDS dest must be wave-uniform base; lane i
// lands at base + i*16B (guide §5 caveat).
__device__ __forceinline__ void gld_lds16(const void* g, void* l) {
  __builtin_amdgcn_global_load_lds(
      (const __attribute__((address_space(1))) unsigned int*)g,
      (__attribute__((address_space(3))) unsigned int*)l, 16, 0, 0);
}

// ---------------- fp32 -> bf16 conversion (query, keys, q_w, k_w fused) ----
__global__ void cvt_all(const float* __restrict__ q, const float* __restrict__ k,
                        const float* __restrict__ qw, const float* __restrict__ kw,
                        bf16* __restrict__ qo, bf16* __restrict__ ko,
                        bf16* __restrict__ qwo, bf16* __restrict__ kwo,
                        int nq, int nk, int nw) {
  const long total = ((long)nq + nk + 2L * nw) >> 3;   // all sizes % 8 == 0
  for (long i = (long)blockIdx.x * blockDim.x + threadIdx.x; i < total;
       i += (long)gridDim.x * blockDim.x) {
    long e = i << 3;
    const float* src; bf16* dst;
    if (e < nq)                       { src = q  + e;               dst = qo  + e; }
    else if (e < (long)nq + nk)       { src = k  + (e - nq);        dst = ko  + (e - nq); }
    else if (e < (long)nq + nk + nw)  { src = qw + (e - nq - nk);   dst = qwo + (e - nq - nk); }
    else                              { src = kw + (e - nq - nk - nw); dst = kwo + (e - nq - nk - nw); }
    float4 a = *(const float4*)(src);
    float4 b = *(const float4*)(src + 4);
    bf16 t[8];
    t[0] = __float2bfloat16(a.x); t[1] = __float2bfloat16(a.y);
    t[2] = __float2bfloat16(a.z); t[3] = __float2bfloat16(a.w);
    t[4] = __float2bfloat16(b.x); t[5] = __float2bfloat16(b.y);
    t[6] = __float2bfloat16(b.z); t[7] = __float2bfloat16(b.w);
    *(short8*)(dst) = *(short8*)(t);
  }
}

// ---------------- shared 128x128 A·B^T core (m97 structure) ---------------
// A: [M][K] row-major bf16, Bm: [N][K] row-major bf16, K multiple of 32.
// 256 threads = 4 waves; wave computes 64x64 via 4x4 grid of 16x16x32 MFMAs.
__device__ __forceinline__ void gemm_bt_core(const bf16* __restrict__ A,
                                             const bf16* __restrict__ Bm,
                                             int m0, int n0, int K,
                                             bf16* sA, bf16* sB,
                                             floatx4 acc[4][4]) {
  const int tid  = threadIdx.x;
  const int lane = tid & 63;
  const int w    = tid >> 6;           // wave 0..3
  const int wm   = (w >> 1) * 64;      // 2x2 wave grid over 128x128
  const int wn   = (w & 1) * 64;
  const int st_row = lane >> 2;        // staging: 0..15 rows per 1KB issue
  const int st_col = (lane & 3) * 8;   // 4x 16B chunks per 64B row
  const int frag_m = lane & 15;        // MFMA A/B operand: [m|n = lane&15][k = (lane>>4)*8 + j]
  const int frag_k = (lane >> 4) * 8;

  #pragma unroll
  for (int mi = 0; mi < 4; ++mi)
    #pragma unroll
    for (int ni = 0; ni < 4; ++ni)
      acc[mi][ni] = (floatx4){0.f, 0.f, 0.f, 0.f};

  for (int kt = 0; kt < K; kt += 32) {
    // stage A-tile [128][32] and B-tile [128][32] (8KB each): 2 issues/wave each
    #pragma unroll
    for (int j = 0; j < 2; ++j) {
      const int r = (w << 5) + (j << 4);               // wave-uniform region start row
      const bf16* ga = A  + (size_t)(m0 + r + st_row) * K + kt + st_col;
      const bf16* gb = Bm + (size_t)(n0 + r + st_row) * K + kt + st_col;
      gld_lds16(ga, sA + r * 32);
      gld_lds16(gb, sB + r * 32);
    }
    __syncthreads();   // compiler emits s_waitcnt vmcnt(0) before s_barrier

    short8 af[4], bfv[4];
    const bf16* pa = sA + (wm + frag_m) * 32 + frag_k;
    const bf16* pb = sB + (wn + frag_m) * 32 + frag_k;
    #pragma unroll
    for (int i = 0; i < 4; ++i) af[i]  = *(const short8*)(pa + i * 16 * 32);
    #pragma unroll
    for (int i = 0; i < 4; ++i) bfv[i] = *(const short8*)(pb + i * 16 * 32);
    #pragma unroll
    for (int mi = 0; mi < 4; ++mi)
      #pragma unroll
      for (int ni = 0; ni < 4; ++ni)
        acc[mi][ni] = __builtin_amdgcn_mfma_f32_16x16x32_bf16(af[mi], bfv[ni],
                                                              acc[mi][ni], 0, 0, 0);
    __syncthreads();   // protect LDS before next stage overwrites
  }
}

// ---------------- projection: C_bf16 = A·W^T + bias ------------------------
__global__ __launch_bounds__(256) void proj_gemm(const bf16* __restrict__ A,
                                                 const bf16* __restrict__ W,
                                                 const float* __restrict__ bias,
                                                 bf16* __restrict__ out) {
  __shared__ bf16 sA[128 * 32];
  __shared__ bf16 sB[128 * 32];
  const int m0 = blockIdx.x * 128;
  const int n0 = blockIdx.y * 128;
  floatx4 acc[4][4];
  gemm_bt_core(A, W, m0, n0, 512, sA, sB, acc);

  const int lane = threadIdx.x & 63;
  const int w = threadIdx.x >> 6;
  const int wm = (w >> 1) * 64, wn = (w & 1) * 64;
  const int col = lane & 15;             // C/D: col = lane&15, row = (lane>>4)*4 + reg
  const int rbase = (lane >> 4) * 4;
  #pragma unroll
  for (int ni = 0; ni < 4; ++ni) {
    const int gn = n0 + wn + ni * 16 + col;
    const float b = bias[gn];
    #pragma unroll
    for (int mi = 0; mi < 4; ++mi) {
      const int gm = m0 + wm + mi * 16 + rbase;
      #pragma unroll
      for (int r = 0; r < 4; ++r)
        out[(size_t)(gm + r) * 512 + gn] = __float2bfloat16(acc[mi][ni][r] + b);
    }
  }
}

// ---------------- QK^T: out_f32 = (Q·K^T)/64, mask -> -inf -----------------
__global__ __launch_bounds__(256) void qk_gemm(const bf16* __restrict__ Q,
                                               const bf16* __restrict__ Kp,
                                               const unsigned char* __restrict__ mask,
                                               float* __restrict__ out) {
  __shared__ bf16 sA[128 * 32];
  __shared__ bf16 sB[128 * 32];
  const int b = blockIdx.z;
  const bf16* A  = Q  + (size_t)b * 2048 * 512;
  const bf16* Bm = Kp + (size_t)b * 4096 * 512;
  float* ob = out + (size_t)b * 2048 * 4096;
  const unsigned char* mb = mask + (size_t)b * 4096;
  const int m0 = blockIdx.x * 128;
  const int n0 = blockIdx.y * 128;
  floatx4 acc[4][4];
  gemm_bt_core(A, Bm, m0, n0, 512, sA, sB, acc);

  const int lane = threadIdx.x & 63;
  const int w = threadIdx.x >> 6;
  const int wm = (w >> 1) * 64, wn = (w & 1) * 64;
  const int col = lane & 15;
  const int rbase = (lane >> 4) * 4;
  const float scale = 1.0f / 64.0f;      // 1 / (N_HEADS * sqrt(HEAD_DIM)) = 1/(8*8)
  #pragma unroll
  for (int ni = 0; ni < 4; ++ni) {
    const int gn = n0 + wn + ni * 16 + col;
    const bool msk = mb[gn] != 0;
    #pragma unroll
    for (int mi = 0; mi < 4; ++mi) {
      const int gm = m0 + wm + mi * 16 + rbase;
      #pragma unroll
      for (int r = 0; r < 4; ++r)
        ob[(size_t)(gm + r) * 4096 + gn] = msk ? NEG_INF : acc[mi][ni][r] * scale;
    }
  }
}

extern "C" void kernel_launch(void* const* d_in, const int* in_sizes, int n_in,
                              void* d_out, int out_size, void* d_ws, size_t ws_size,
                              hipStream_t stream) {
  const float* query = (const float*)d_in[0];
  const float* keys  = (const float*)d_in[1];
  const unsigned char* mask = (const unsigned char*)d_in[2];  // numpy bool = 1B; all-zero either way
  const float* q_w = (const float*)d_in[3];
  const float* q_b = (const float*)d_in[4];
  const float* k_w = (const float*)d_in[5];
  const float* k_b = (const float*)d_in[6];
  float* out = (float*)d_out;

  const int B = 4, T = 2048, S = 4096, D = 512;
  const int nq = B * T * D;   // 4194304
  const int nk = B * S * D;   // 8388608
  const int nw = D * D;       // 262144

  // workspace carve (bf16): query, keys, q_w, k_w, Q_proj, K_proj  (~49 MiB)
  char* ws = (char*)d_ws;
  bf16* query_bf = (bf16*)(ws);
  bf16* keys_bf  = (bf16*)(ws + (size_t)nq * 2);
  bf16* qw_bf    = (bf16*)(ws + (size_t)(nq + nk) * 2);
  bf16* kw_bf    = (bf16*)(ws + (size_t)(nq + nk + nw) * 2);
  bf16* q_proj   = (bf16*)(ws + (size_t)(nq + nk + 2 * nw) * 2);
  bf16* k_proj   = (bf16*)(ws + (size_t)(nq + nk + 2 * nw + nq) * 2);

  cvt_all<<<2048, 256, 0, stream>>>(query, keys, q_w, k_w,
                                    query_bf, keys_bf, qw_bf, kw_bf, nq, nk, nw);
  proj_gemm<<<dim3(B * T / 128, D / 128), 256, 0, stream>>>(query_bf, qw_bf, q_b, q_proj);
  proj_gemm<<<dim3(B * S / 128, D / 128), 256, 0, stream>>>(keys_bf, kw_bf, k_b, k_proj);
  qk_gemm<<<dim3(T / 128, S / 128, B), 256, 0, stream>>>(q_proj, k_proj, mask, out);
}

// Round 2
// 239.748 us; speedup vs baseline: 1.1439x; 1.1439x over previous
//
#include <hip/hip_runtime.h>
#include <hip/hip_bf16.h>

using bf16 = __hip_bfloat16;
typedef __attribute__((ext_vector_type(8))) short short8;   // 8 bf16 = 4 VGPRs (MFMA a/b frag)
typedef __attribute__((ext_vector_type(4))) float floatx4;  // MFMA c/d frag

#define NEG_INF (-__builtin_huge_valf())

// async global->LDS, 16B per lane. LDS dest must be wave-uniform base; lane i
// lands at base + i*16B (guide §5 caveat).
__device__ __forceinline__ void gld_lds16(const void* g, void* l) {
  __builtin_amdgcn_global_load_lds(
      (const __attribute__((address_space(1))) unsigned int*)g,
      (__attribute__((address_space(3))) unsigned int*)l, 16, 0, 0);
}

__device__ __forceinline__ void cvt8(const float4& a, const float4& b, bf16* t) {
  t[0] = __float2bfloat16(a.x); t[1] = __float2bfloat16(a.y);
  t[2] = __float2bfloat16(a.z); t[3] = __float2bfloat16(a.w);
  t[4] = __float2bfloat16(b.x); t[5] = __float2bfloat16(b.y);
  t[6] = __float2bfloat16(b.z); t[7] = __float2bfloat16(b.w);
}

// ---------------- fused projection: out_bf16 = cvt(A_f32)·cvt(W_f32)^T + b --
// One launch covers BOTH projections: blockIdx.x in [0,64) -> Q rows,
// [64,192) -> K rows. 768 blocks total = 3 blocks/CU (restores wave overlap
// that 1 block/CU denied the separate launches). fp32 loaded to VGPR,
// converted, ds_write_b128 staged (no global_load_lds on this path).
__global__ __launch_bounds__(256) void proj_fused(const float* __restrict__ X,
                                                  const float* __restrict__ Y,
                                                  const float* __restrict__ qw,
                                                  const float* __restrict__ kw,
                                                  const float* __restrict__ qb,
                                                  const float* __restrict__ kb,
                                                  bf16* __restrict__ qo,
                                                  bf16* __restrict__ ko) {
  __shared__ bf16 sA[128 * 32];
  __shared__ bf16 sB[128 * 32];
  const int mt = blockIdx.x;
  const bool isQ = mt < 64;
  const float* A    = isQ ? X  : Y;
  const float* W    = isQ ? qw : kw;
  const float* bias = isQ ? qb : kb;
  bf16* out         = isQ ? qo : ko;
  const int m0 = (isQ ? mt : mt - 64) * 128;
  const int n0 = blockIdx.y * 128;

  const int tid  = threadIdx.x;
  const int lane = tid & 63;
  const int w    = tid >> 6;
  const int wm   = (w >> 1) * 64;
  const int wn   = (w & 1) * 64;
  const int st_row = lane >> 2;
  const int st_col = (lane & 3) * 8;
  const int frag_m = lane & 15;
  const int frag_k = (lane >> 4) * 8;

  floatx4 acc[4][4];
  #pragma unroll
  for (int mi = 0; mi < 4; ++mi)
    #pragma unroll
    for (int ni = 0; ni < 4; ++ni)
      acc[mi][ni] = (floatx4){0.f, 0.f, 0.f, 0.f};

  for (int kt = 0; kt < 512; kt += 32) {
    #pragma unroll
    for (int j = 0; j < 2; ++j) {
      const int r = (w << 5) + (j << 4);
      const int row = r + st_row;
      const float* ga = A + (size_t)(m0 + row) * 512 + kt + st_col;
      const float* gb = W + (size_t)(n0 + row) * 512 + kt + st_col;
      float4 a0 = *(const float4*)ga;
      float4 a1 = *(const float4*)(ga + 4);
      float4 b0 = *(const float4*)gb;
      float4 b1 = *(const float4*)(gb + 4);
      bf16 ta[8], tb[8];
      cvt8(a0, a1, ta);
      cvt8(b0, b1, tb);
      *(short8*)(sA + row * 32 + st_col) = *(short8*)ta;
      *(short8*)(sB + row * 32 + st_col) = *(short8*)tb;
    }
    __syncthreads();

    short8 af[4], bfv[4];
    const bf16* pa = sA + (wm + frag_m) * 32 + frag_k;
    const bf16* pb = sB + (wn + frag_m) * 32 + frag_k;
    #pragma unroll
    for (int i = 0; i < 4; ++i) af[i]  = *(const short8*)(pa + i * 16 * 32);
    #pragma unroll
    for (int i = 0; i < 4; ++i) bfv[i] = *(const short8*)(pb + i * 16 * 32);
    #pragma unroll
    for (int mi = 0; mi < 4; ++mi)
      #pragma unroll
      for (int ni = 0; ni < 4; ++ni)
        acc[mi][ni] = __builtin_amdgcn_mfma_f32_16x16x32_bf16(af[mi], bfv[ni],
                                                              acc[mi][ni], 0, 0, 0);
    __syncthreads();
  }

  const int col = lane & 15;             // C/D: col = lane&15, row = (lane>>4)*4 + reg
  const int rbase = (lane >> 4) * 4;
  #pragma unroll
  for (int ni = 0; ni < 4; ++ni) {
    const int gn = n0 + wn + ni * 16 + col;
    const float b = bias[gn];
    #pragma unroll
    for (int mi = 0; mi < 4; ++mi) {
      const int gm = m0 + wm + mi * 16 + rbase;
      #pragma unroll
      for (int r = 0; r < 4; ++r)
        out[(size_t)(gm + r) * 512 + gn] = __float2bfloat16(acc[mi][ni][r] + b);
    }
  }
}

// ---------------- QK^T: out_f32 = (Q·K^T)/64, mask -> -inf -----------------
// m97 structure: global_load_lds width-16 staging, 16x16x32 bf16 MFMA,
// 2048 blocks = 8/CU.
__global__ __launch_bounds__(256) void qk_gemm(const bf16* __restrict__ Q,
                                               const bf16* __restrict__ Kp,
                                               const unsigned char* __restrict__ mask,
                                               float* __restrict__ out) {
  __shared__ bf16 sA[128 * 32];
  __shared__ bf16 sB[128 * 32];
  const int b = blockIdx.z;
  const bf16* A  = Q  + (size_t)b * 2048 * 512;
  const bf16* Bm = Kp + (size_t)b * 4096 * 512;
  float* ob = out + (size_t)b * 2048 * 4096;
  const unsigned char* mb = mask + (size_t)b * 4096;
  const int m0 = blockIdx.x * 128;
  const int n0 = blockIdx.y * 128;

  const int tid  = threadIdx.x;
  const int lane = tid & 63;
  const int w    = tid >> 6;
  const int wm   = (w >> 1) * 64;
  const int wn   = (w & 1) * 64;
  const int st_row = lane >> 2;
  const int st_col = (lane & 3) * 8;
  const int frag_m = lane & 15;
  const int frag_k = (lane >> 4) * 8;

  floatx4 acc[4][4];
  #pragma unroll
  for (int mi = 0; mi < 4; ++mi)
    #pragma unroll
    for (int ni = 0; ni < 4; ++ni)
      acc[mi][ni] = (floatx4){0.f, 0.f, 0.f, 0.f};

  for (int kt = 0; kt < 512; kt += 32) {
    #pragma unroll
    for (int j = 0; j < 2; ++j) {
      const int r = (w << 5) + (j << 4);
      const bf16* ga = A  + (size_t)(m0 + r + st_row) * 512 + kt + st_col;
      const bf16* gb = Bm + (size_t)(n0 + r + st_row) * 512 + kt + st_col;
      gld_lds16(ga, sA + r * 32);
      gld_lds16(gb, sB + r * 32);
    }
    __syncthreads();

    short8 af[4], bfv[4];
    const bf16* pa = sA + (wm + frag_m) * 32 + frag_k;
    const bf16* pb = sB + (wn + frag_m) * 32 + frag_k;
    #pragma unroll
    for (int i = 0; i < 4; ++i) af[i]  = *(const short8*)(pa + i * 16 * 32);
    #pragma unroll
    for (int i = 0; i < 4; ++i) bfv[i] = *(const short8*)(pb + i * 16 * 32);
    #pragma unroll
    for (int mi = 0; mi < 4; ++mi)
      #pragma unroll
      for (int ni = 0; ni < 4; ++ni)
        acc[mi][ni] = __builtin_amdgcn_mfma_f32_16x16x32_bf16(af[mi], bfv[ni],
                                                              acc[mi][ni], 0, 0, 0);
    __syncthreads();
  }

  const int col = lane & 15;
  const int rbase = (lane >> 4) * 4;
  const float scale = 1.0f / 64.0f;      // 1 / (N_HEADS * sqrt(HEAD_DIM))
  #pragma unroll
  for (int ni = 0; ni < 4; ++ni) {
    const int gn = n0 + wn + ni * 16 + col;
    const bool msk = mb[gn] != 0;
    #pragma unroll
    for (int mi = 0; mi < 4; ++mi) {
      const int gm = m0 + wm + mi * 16 + rbase;
      #pragma unroll
      for (int r = 0; r < 4; ++r)
        ob[(size_t)(gm + r) * 4096 + gn] = msk ? NEG_INF : acc[mi][ni][r] * scale;
    }
  }
}

extern "C" void kernel_launch(void* const* d_in, const int* in_sizes, int n_in,
                              void* d_out, int out_size, void* d_ws, size_t ws_size,
                              hipStream_t stream) {
  const float* query = (const float*)d_in[0];
  const float* keys  = (const float*)d_in[1];
  const unsigned char* mask = (const unsigned char*)d_in[2];  // numpy bool = 1B
  const float* q_w = (const float*)d_in[3];
  const float* q_b = (const float*)d_in[4];
  const float* k_w = (const float*)d_in[5];
  const float* k_b = (const float*)d_in[6];
  float* out = (float*)d_out;

  const int B = 4, T = 2048, S = 4096, D = 512;
  const int nq = B * T * D;   // 4194304
  const int nk = B * S * D;   // 8388608

  // workspace carve (bf16): Q_proj (16 MiB), K_proj (32 MiB)
  char* ws = (char*)d_ws;
  bf16* q_proj = (bf16*)(ws);
  bf16* k_proj = (bf16*)(ws + (size_t)nq * 2);

  // 192 M-tiles (64 Q + 128 K) x 4 N-tiles = 768 blocks = 3/CU
  proj_fused<<<dim3(192, D / 128), 256, 0, stream>>>(query, keys, q_w, k_w,
                                                     q_b, k_b, q_proj, k_proj);
  qk_gemm<<<dim3(T / 128, S / 128, B), 256, 0, stream>>>(q_proj, k_proj, mask, out);
}